// Round 5
// baseline (937.950 us; speedup 1.0000x reference)
//
#include <hip/hip_runtime.h>
#include <hip/hip_bf16.h>

typedef __bf16 bf16_t;
typedef __bf16 bf16x4 __attribute__((ext_vector_type(4)));
typedef __bf16 bf16x8 __attribute__((ext_vector_type(8)));
typedef float  f32x4  __attribute__((ext_vector_type(4)));

#define GLD_LDS16(gptr, lptr)                                                        \
    __builtin_amdgcn_global_load_lds((__attribute__((address_space(1))) void*)(gptr),\
                                     (__attribute__((address_space(3))) void*)(lptr),\
                                     16, 0, 0)

constexpr int Bc = 2, Tc = 2048, Ec = 2048, Hc = 16, Dc = 128;
constexpr int Mtok = Bc * Tc;  // 4096

__device__ __forceinline__ bf16x8 cvt8(const float* p) {
    f32x4 a = *(const f32x4*)p;
    f32x4 b = *(const f32x4*)(p + 4);
    bf16x8 r;
    r[0] = (bf16_t)a[0]; r[1] = (bf16_t)a[1];
    r[2] = (bf16_t)a[2]; r[3] = (bf16_t)a[3];
    r[4] = (bf16_t)b[0]; r[5] = (bf16_t)b[1];
    r[6] = (bf16_t)b[2]; r[7] = (bf16_t)b[3];
    return r;
}

// ---------------------------------------------------------------------------
// fp32 -> bf16 bulk convert (x -> xb), 8 elems/thread
// ---------------------------------------------------------------------------
__global__ void convert_bf16(const float* __restrict__ src, bf16_t* __restrict__ dst) {
    size_t i = ((size_t)blockIdx.x * 256 + threadIdx.x) * 8;
    *(bf16x8*)&dst[i] = cvt8(src + i);
}

// ---------------------------------------------------------------------------
// GEMM: C[m][n] = sum_k A[m][k]*W[n][k] + bias[n]
// A: [M][K] bf16 (staged via global_load_lds, m97 pattern)
// W: [N][K] fp32 (register-staged with fp32->bf16 convert)
// MODE 0: fp32 out [M][N]; MODE 1: bf16 out [B,H,T,D]; MODE 2: bf16 out
// [B,H,D,T] (transposed V epilogue, 8B-packed stores).
// 128x128 tile, BK=32, 4 waves (2x2 of 64x64), plain [row][k] LDS.
// ---------------------------------------------------------------------------
template <int MODE>
__global__ __launch_bounds__(256) void gemm_bt(const bf16_t* __restrict__ A,
                                               const float* __restrict__ W,
                                               const float* __restrict__ bias,
                                               bf16_t* __restrict__ outb,
                                               float* __restrict__ outf,
                                               int M, int N, int K) {
    __shared__ __align__(16) bf16_t ldsA[128 * 32];
    __shared__ __align__(16) bf16_t ldsB[128 * 32];

    const int tid  = threadIdx.x;
    const int wave = tid >> 6;
    const int lane = tid & 63;
    const int g    = lane >> 4;
    const int n16  = lane & 15;
    const int m0 = blockIdx.x * 128;
    const int n0 = blockIdx.y * 128;
    const int row_off = (wave >> 1) * 64;
    const int col_off = (wave & 1) * 64;

    f32x4 acc[4][4] = {};

    // slot s = tid (+256) -> row s>>2 of tile, 16B-chunk s&3
    const int r0 = tid >> 2;
    const int cc = tid & 3;
    const size_t a0 = (size_t)(m0 + r0) * K + cc * 8;
    const size_t a1 = (size_t)(m0 + r0 + 64) * K + cc * 8;
    const float* pb0 = W + (size_t)(n0 + r0) * K + cc * 8;
    const float* pb1 = W + (size_t)(n0 + r0 + 64) * K + cc * 8;

    for (int k0 = 0; k0 < K; k0 += 32) {
        bf16x8 vb0 = cvt8(pb0 + k0);
        bf16x8 vb1 = cvt8(pb1 + k0);
        __syncthreads();  // prior tile's readers done
        GLD_LDS16(A + a0 + k0, &ldsA[(wave * 64) * 8]);
        GLD_LDS16(A + a1 + k0, &ldsA[(256 + wave * 64) * 8]);
        *(bf16x8*)&ldsB[(size_t)tid * 8]         = vb0;
        *(bf16x8*)&ldsB[(size_t)(256 + tid) * 8] = vb1;
        __syncthreads();  // drains vmcnt (GLD) + lgkmcnt (ds_write)

        bf16x8 af[4], bfr[4];
#pragma unroll
        for (int mt = 0; mt < 4; ++mt)
            af[mt] = *(const bf16x8*)&ldsA[(row_off + mt * 16 + n16) * 32 + g * 8];
#pragma unroll
        for (int nt = 0; nt < 4; ++nt)
            bfr[nt] = *(const bf16x8*)&ldsB[(col_off + nt * 16 + n16) * 32 + g * 8];
#pragma unroll
        for (int mt = 0; mt < 4; ++mt)
#pragma unroll
            for (int nt = 0; nt < 4; ++nt)
                acc[mt][nt] = __builtin_amdgcn_mfma_f32_16x16x32_bf16(
                    af[mt], bfr[nt], acc[mt][nt], 0, 0, 0);
    }

    // C/D: col(n)=lane&15, row(m)=(lane>>4)*4+reg  (m89-verified)
#pragma unroll
    for (int nt = 0; nt < 4; ++nt) {
        int n = n0 + col_off + nt * 16 + n16;
        float bn = bias[n];
#pragma unroll
        for (int mt = 0; mt < 4; ++mt) {
            int mb = m0 + row_off + mt * 16 + g * 4;
            if (MODE == 2) {
                // vt[((b*H+h)*D + d)*T + t], 4 consecutive t packed
                int b = mb >> 11, t = mb & (Tc - 1);
                int h = n >> 7, d = n & (Dc - 1);
                bf16x4 pk;
#pragma unroll
                for (int r = 0; r < 4; ++r) pk[r] = (bf16_t)(acc[mt][nt][r] + bn);
                *(bf16x4*)&outb[(((size_t)(b * Hc + h)) * Dc + d) * Tc + t] = pk;
            } else {
#pragma unroll
                for (int r = 0; r < 4; ++r) {
                    int m = mb + r;
                    float cv = acc[mt][nt][r] + bn;
                    if (MODE == 0) {
                        outf[(size_t)m * N + n] = cv;
                    } else {
                        int b = m >> 11, t = m & (Tc - 1);
                        int h = n >> 7, d = n & (Dc - 1);
                        outb[(((size_t)(b * Hc + h)) * Tc + t) * Dc + d] = (bf16_t)cv;
                    }
                }
            }
        }
    }
}

// ---------------------------------------------------------------------------
// RoPE in-place on q,k [B,H,T,D]; positions 1-indexed (t+1).
// ---------------------------------------------------------------------------
__global__ void rope_kernel(bf16_t* __restrict__ q, bf16_t* __restrict__ k) {
    int row = blockIdx.x * 4 + (threadIdx.x >> 6);  // (b*H+h)*T + t
    int d   = threadIdx.x & 63;
    int t   = row & (Tc - 1);
    float theta = powf(10000.0f, -(float)d * (1.0f / 64.0f));
    float ang   = (float)(t + 1) * theta;
    float sv, cv;
    sincosf(ang, &sv, &cv);
    size_t base = (size_t)row * Dc;
    float q1 = (float)q[base + d], q2 = (float)q[base + d + 64];
    q[base + d]      = (bf16_t)(q1 * cv - q2 * sv);
    q[base + d + 64] = (bf16_t)(q2 * cv + q1 * sv);
    float k1 = (float)k[base + d], k2 = (float)k[base + d + 64];
    k[base + d]      = (bf16_t)(k1 * cv - k2 * sv);
    k[base + d + 64] = (bf16_t)(k2 * cv + k1 * sv);
}

// ---------------------------------------------------------------------------
// Causal flash attention, barrier-free K-loop.
// q,k: [B,H,T,D] bf16 (post-RoPE); vt: [B,H,D,T] bf16; out att: [B,T,E] bf16.
// Block = 4 waves = 64 queries. K/V fragments loaded DIRECTLY from global
// (contiguous 16B per lane; tiles are L1/L2-resident). Only the per-wave
// P round-trip uses LDS -> no __syncthreads in the loop.
// qt reversed so heavy (large-kt-count) blocks dispatch first.
// ---------------------------------------------------------------------------
constexpr int PP = 64 + 8;  // p_lds row pitch

__global__ __launch_bounds__(256) void attn_kernel(const bf16_t* __restrict__ q,
                                                   const bf16_t* __restrict__ kmat,
                                                   const bf16_t* __restrict__ vt,
                                                   bf16_t* __restrict__ out) {
    __shared__ __align__(16) bf16_t p_lds[4 * 16 * PP];  // per-wave [q][key]

    const int tid  = threadIdx.x;
    const int wave = tid >> 6, lane = tid & 63;
    const int g = lane >> 4, n16 = lane & 15;
    const int qt = (int)(gridDim.x - 1) - (int)blockIdx.x;  // heavy first
    const int bh = blockIdx.y;
    const int q0 = qt * 64;
    const size_t base = (size_t)bh * Tc * Dc;

    // persistent Q fragments: A[m=n16][k=g*8 + kk*32 + j]
    bf16x8 qf[4];
    {
        const bf16_t* qp = q + base + (size_t)(q0 + wave * 16 + n16) * Dc + g * 8;
#pragma unroll
        for (int kk = 0; kk < 4; ++kk) qf[kk] = *(const bf16x8*)(qp + kk * 32);
    }

    float m_run[4], l_run[4];
#pragma unroll
    for (int r = 0; r < 4; ++r) { m_run[r] = -1e30f; l_run[r] = 0.0f; }
    f32x4 o_acc[8] = {};

    const float scale = 0.08838834764831845f;  // 1/sqrt(128)
    bf16_t* pw = &p_lds[wave * 16 * PP];

    for (int kt = 0; kt <= qt; ++kt) {
        const int k0 = kt * 64;
        const bf16_t* kb = kmat + base + (size_t)k0 * Dc;

        // S = Q K^T: B-frag kf[n=key=nt*16+n16][k=d=kk*32+g*8+j] direct global
        f32x4 s_acc[4];
#pragma unroll
        for (int nt = 0; nt < 4; ++nt) {
            const bf16_t* kr = kb + (size_t)(nt * 16 + n16) * Dc + g * 8;
            f32x4 a = {};
#pragma unroll
            for (int kk = 0; kk < 4; ++kk) {
                bf16x8 kf = *(const bf16x8*)(kr + kk * 32);
                a = __builtin_amdgcn_mfma_f32_16x16x32_bf16(qf[kk], kf, a, 0, 0, 0);
            }
            s_acc[nt] = a;
        }

        // scale + causal mask (C/D: col=key=n16, row=q=g*4+r)
#pragma unroll
        for (int nt = 0; nt < 4; ++nt) {
            int key = k0 + nt * 16 + n16;
#pragma unroll
            for (int r = 0; r < 4; ++r) {
                int qq = q0 + wave * 16 + g * 4 + r;
                float v = s_acc[nt][r] * scale;
                s_acc[nt][r] = (key <= qq) ? v : -1e30f;
            }
        }

        // online softmax; row spans the 16 lanes sharing quad g
        float alpha[4];
#pragma unroll
        for (int r = 0; r < 4; ++r) {
            float rm = fmaxf(fmaxf(s_acc[0][r], s_acc[1][r]),
                             fmaxf(s_acc[2][r], s_acc[3][r]));
            rm = fmaxf(rm, __shfl_xor(rm, 1, 16));
            rm = fmaxf(rm, __shfl_xor(rm, 2, 16));
            rm = fmaxf(rm, __shfl_xor(rm, 4, 16));
            rm = fmaxf(rm, __shfl_xor(rm, 8, 16));
            float m_new = fmaxf(m_run[r], rm);
            alpha[r] = __expf(m_run[r] - m_new);
            m_run[r] = m_new;
            float sum = 0.0f;
#pragma unroll
            for (int nt = 0; nt < 4; ++nt) {
                float p = __expf(s_acc[nt][r] - m_new);
                s_acc[nt][r] = p;
                sum += p;
            }
            sum += __shfl_xor(sum, 1, 16);
            sum += __shfl_xor(sum, 2, 16);
            sum += __shfl_xor(sum, 4, 16);
            sum += __shfl_xor(sum, 8, 16);
            l_run[r] = l_run[r] * alpha[r] + sum;
        }
#pragma unroll
        for (int dt = 0; dt < 8; ++dt)
#pragma unroll
            for (int r = 0; r < 4; ++r) o_acc[dt][r] *= alpha[r];

        // P (C/D) -> per-wave LDS [q][key] (wave-private: no barrier needed)
#pragma unroll
        for (int nt = 0; nt < 4; ++nt) {
            int key = nt * 16 + n16;
#pragma unroll
            for (int r = 0; r < 4; ++r)
                pw[(g * 4 + r) * PP + key] = (bf16_t)s_acc[nt][r];
        }

        // A-frag pf[m=q=n16][k=key=kk*32+g*8+j] from wave-private LDS
        bf16x8 pf[2];
#pragma unroll
        for (int kk = 0; kk < 2; ++kk)
            pf[kk] = *(const bf16x8*)&pw[n16 * PP + kk * 32 + g * 8];

        // O += P V: B-frag vf[n=d=dt*16+n16][k=key=kk*32+g*8+j] direct global
        const bf16_t* vb = vt + base + k0 + (size_t)n16 * Tc + g * 8;
#pragma unroll
        for (int dt = 0; dt < 8; ++dt) {
            const bf16_t* vr = vb + (size_t)(dt * 16) * Tc;
#pragma unroll
            for (int kk = 0; kk < 2; ++kk) {
                bf16x8 vf = *(const bf16x8*)(vr + kk * 32);
                o_acc[dt] = __builtin_amdgcn_mfma_f32_16x16x32_bf16(
                    pf[kk], vf, o_acc[dt], 0, 0, 0);
            }
        }
    }

    // epilogue: O / l -> att [B,T,E]
    const int b = bh >> 4, h = bh & 15;
    float inv_l[4];
#pragma unroll
    for (int r = 0; r < 4; ++r) inv_l[r] = 1.0f / l_run[r];
#pragma unroll
    for (int dt = 0; dt < 8; ++dt) {
        int d = dt * 16 + n16;
#pragma unroll
        for (int r = 0; r < 4; ++r) {
            int qq = q0 + wave * 16 + g * 4 + r;
            out[((size_t)(b * Tc + qq)) * Ec + h * Dc + d] =
                (bf16_t)(o_acc[dt][r] * inv_l[r]);
        }
    }
}

// ---------------------------------------------------------------------------
extern "C" void kernel_launch(void* const* d_in, const int* in_sizes, int n_in,
                              void* d_out, int out_size, void* d_ws, size_t ws_size,
                              hipStream_t stream) {
    const float* x  = (const float*)d_in[0];
    const float* Wq = (const float*)d_in[1];
    const float* bq = (const float*)d_in[2];
    const float* Wk = (const float*)d_in[3];
    const float* bk = (const float*)d_in[4];
    const float* Wv = (const float*)d_in[5];
    const float* bv = (const float*)d_in[6];
    const float* Wo = (const float*)d_in[7];
    const float* bo = (const float*)d_in[8];
    float* out = (float*)d_out;

    char* ws = (char*)d_ws;
    const size_t sz = (size_t)Bc * Hc * Tc * Dc * sizeof(bf16_t);  // 16.78 MB
    bf16_t* q   = (bf16_t*)(ws);            // R0
    bf16_t* k   = (bf16_t*)(ws + sz);       // R1
    bf16_t* vt  = (bf16_t*)(ws + 2 * sz);   // R2 (written transposed by V-GEMM)
    bf16_t* xb  = (bf16_t*)(ws + 3 * sz);   // R3: xb during projections...
    bf16_t* att = xb;                       // ...then att (xb dead post-QKV)

    dim3 ggrid(Mtok / 128, Ec / 128);  // 32 x 16
    convert_bf16<<<Mtok * Ec / (256 * 8), 256, 0, stream>>>(x, xb);
    gemm_bt<1><<<ggrid, 256, 0, stream>>>(xb, Wq, bq, q, nullptr, Mtok, Ec, Ec);
    gemm_bt<1><<<ggrid, 256, 0, stream>>>(xb, Wk, bk, k, nullptr, Mtok, Ec, Ec);
    gemm_bt<2><<<ggrid, 256, 0, stream>>>(xb, Wv, bv, vt, nullptr, Mtok, Ec, Ec);
    rope_kernel<<<Bc * Hc * Tc / 4, 256, 0, stream>>>(q, k);
    attn_kernel<<<dim3(Tc / 64, Bc * Hc), 256, 0, stream>>>(q, k, vt, att);
    gemm_bt<0><<<ggrid, 256, 0, stream>>>(att, Wo, bo, nullptr, out, Mtok, Ec, Ec);
}

// Round 6
// 502.573 us; speedup vs baseline: 1.8663x; 1.8663x over previous
//
#include <hip/hip_runtime.h>
#include <hip/hip_bf16.h>

typedef __bf16 bf16_t;
typedef __bf16 bf16x4 __attribute__((ext_vector_type(4)));
typedef __bf16 bf16x8 __attribute__((ext_vector_type(8)));
typedef float  f32x4  __attribute__((ext_vector_type(4)));

#define GLD_LDS16(gptr, lptr)                                                        \
    __builtin_amdgcn_global_load_lds((__attribute__((address_space(1))) void*)(gptr),\
                                     (__attribute__((address_space(3))) void*)(lptr),\
                                     16, 0, 0)

constexpr int Bc = 2, Tc = 2048, Ec = 2048, Hc = 16, Dc = 128;
constexpr int Mtok = Bc * Tc;  // 4096

__device__ __forceinline__ bf16x8 cvt8(const float* p) {
    f32x4 a = *(const f32x4*)p;
    f32x4 b = *(const f32x4*)(p + 4);
    bf16x8 r;
    r[0] = (bf16_t)a[0]; r[1] = (bf16_t)a[1];
    r[2] = (bf16_t)a[2]; r[3] = (bf16_t)a[3];
    r[4] = (bf16_t)b[0]; r[5] = (bf16_t)b[1];
    r[6] = (bf16_t)b[2]; r[7] = (bf16_t)b[3];
    return r;
}

__global__ void convert_bf16(const float* __restrict__ src, bf16_t* __restrict__ dst) {
    size_t i = ((size_t)blockIdx.x * 256 + threadIdx.x) * 8;
    *(bf16x8*)&dst[i] = cvt8(src + i);
}

// ---------------------------------------------------------------------------
// Fused Q/K/V projection GEMM. A = xb [M][K] bf16 (global_load_lds staging),
// W = Wq/Wk/Wv [N][K] fp32 (register-staged fp32->bf16). Grid (32, 48):
// blockIdx.y selects matrix (y>>4) and n-panel (y&15). Q,K -> [B,H,T,D];
// V -> [B,H,D,T] transposed epilogue. 128x128 tile, BK=32, 4 waves.
// ---------------------------------------------------------------------------
__global__ __launch_bounds__(256) void gemm_qkv(const bf16_t* __restrict__ A,
                                                const float* __restrict__ Wq,
                                                const float* __restrict__ Wk,
                                                const float* __restrict__ Wv,
                                                const float* __restrict__ bq,
                                                const float* __restrict__ bk,
                                                const float* __restrict__ bv,
                                                bf16_t* __restrict__ qo,
                                                bf16_t* __restrict__ ko,
                                                bf16_t* __restrict__ vto) {
    __shared__ __align__(16) bf16_t ldsA[128 * 32];
    __shared__ __align__(16) bf16_t ldsB[128 * 32];

    const int tid  = threadIdx.x;
    const int wave = tid >> 6;
    const int lane = tid & 63;
    const int g    = lane >> 4;
    const int n16  = lane & 15;
    const int m0   = blockIdx.x * 128;
    const int mat  = blockIdx.y >> 4;           // 0=Q 1=K 2=V
    const int n0   = (blockIdx.y & 15) * 128;
    const int row_off = (wave >> 1) * 64;
    const int col_off = (wave & 1) * 64;
    const int K = Ec;

    const float* W    = (mat == 0) ? Wq : (mat == 1) ? Wk : Wv;
    const float* bias = (mat == 0) ? bq : (mat == 1) ? bk : bv;

    f32x4 acc[4][4] = {};

    const int r0 = tid >> 2;
    const int cc = tid & 3;
    const size_t a0 = (size_t)(m0 + r0) * K + cc * 8;
    const size_t a1 = (size_t)(m0 + r0 + 64) * K + cc * 8;
    const float* pb0 = W + (size_t)(n0 + r0) * K + cc * 8;
    const float* pb1 = W + (size_t)(n0 + r0 + 64) * K + cc * 8;

    for (int k0 = 0; k0 < K; k0 += 32) {
        bf16x8 vb0 = cvt8(pb0 + k0);
        bf16x8 vb1 = cvt8(pb1 + k0);
        __syncthreads();
        GLD_LDS16(A + a0 + k0, &ldsA[(wave * 64) * 8]);
        GLD_LDS16(A + a1 + k0, &ldsA[(256 + wave * 64) * 8]);
        *(bf16x8*)&ldsB[(size_t)tid * 8]         = vb0;
        *(bf16x8*)&ldsB[(size_t)(256 + tid) * 8] = vb1;
        __syncthreads();

        bf16x8 af[4], bfr[4];
#pragma unroll
        for (int mt = 0; mt < 4; ++mt)
            af[mt] = *(const bf16x8*)&ldsA[(row_off + mt * 16 + n16) * 32 + g * 8];
#pragma unroll
        for (int nt = 0; nt < 4; ++nt)
            bfr[nt] = *(const bf16x8*)&ldsB[(col_off + nt * 16 + n16) * 32 + g * 8];
#pragma unroll
        for (int mt = 0; mt < 4; ++mt)
#pragma unroll
            for (int nt = 0; nt < 4; ++nt)
                acc[mt][nt] = __builtin_amdgcn_mfma_f32_16x16x32_bf16(
                    af[mt], bfr[nt], acc[mt][nt], 0, 0, 0);
    }

    // C/D: col(n)=lane&15, row(m)=(lane>>4)*4+reg
#pragma unroll
    for (int nt = 0; nt < 4; ++nt) {
        int n = n0 + col_off + nt * 16 + n16;
        float bn = bias[n];
        int h = n >> 7, d = n & (Dc - 1);
#pragma unroll
        for (int mt = 0; mt < 4; ++mt) {
            int mb = m0 + row_off + mt * 16 + g * 4;
            int b = mb >> 11, t = mb & (Tc - 1);
            if (mat == 2) {
                bf16x4 pk;
#pragma unroll
                for (int r = 0; r < 4; ++r) pk[r] = (bf16_t)(acc[mt][nt][r] + bn);
                *(bf16x4*)&vto[(((size_t)(b * Hc + h)) * Dc + d) * Tc + t] = pk;
            } else {
                bf16_t* outb = (mat == 0) ? qo : ko;
#pragma unroll
                for (int r = 0; r < 4; ++r)
                    outb[(((size_t)(b * Hc + h)) * Tc + (t + r)) * Dc + d] =
                        (bf16_t)(acc[mt][nt][r] + bn);
            }
        }
    }
}

// ---------------------------------------------------------------------------
// Output projection GEMM: A = att [M][K] bf16 (GLD), W = Wo fp32, out fp32.
// ---------------------------------------------------------------------------
__global__ __launch_bounds__(256) void gemm_out(const bf16_t* __restrict__ A,
                                                const float* __restrict__ W,
                                                const float* __restrict__ bias,
                                                float* __restrict__ out,
                                                int M, int N, int K) {
    __shared__ __align__(16) bf16_t ldsA[128 * 32];
    __shared__ __align__(16) bf16_t ldsB[128 * 32];

    const int tid  = threadIdx.x;
    const int wave = tid >> 6;
    const int lane = tid & 63;
    const int g    = lane >> 4;
    const int n16  = lane & 15;
    const int m0 = blockIdx.x * 128;
    const int n0 = blockIdx.y * 128;
    const int row_off = (wave >> 1) * 64;
    const int col_off = (wave & 1) * 64;

    f32x4 acc[4][4] = {};

    const int r0 = tid >> 2;
    const int cc = tid & 3;
    const size_t a0 = (size_t)(m0 + r0) * K + cc * 8;
    const size_t a1 = (size_t)(m0 + r0 + 64) * K + cc * 8;
    const float* pb0 = W + (size_t)(n0 + r0) * K + cc * 8;
    const float* pb1 = W + (size_t)(n0 + r0 + 64) * K + cc * 8;

    for (int k0 = 0; k0 < K; k0 += 32) {
        bf16x8 vb0 = cvt8(pb0 + k0);
        bf16x8 vb1 = cvt8(pb1 + k0);
        __syncthreads();
        GLD_LDS16(A + a0 + k0, &ldsA[(wave * 64) * 8]);
        GLD_LDS16(A + a1 + k0, &ldsA[(256 + wave * 64) * 8]);
        *(bf16x8*)&ldsB[(size_t)tid * 8]         = vb0;
        *(bf16x8*)&ldsB[(size_t)(256 + tid) * 8] = vb1;
        __syncthreads();

        bf16x8 af[4], bfr[4];
#pragma unroll
        for (int mt = 0; mt < 4; ++mt)
            af[mt] = *(const bf16x8*)&ldsA[(row_off + mt * 16 + n16) * 32 + g * 8];
#pragma unroll
        for (int nt = 0; nt < 4; ++nt)
            bfr[nt] = *(const bf16x8*)&ldsB[(col_off + nt * 16 + n16) * 32 + g * 8];
#pragma unroll
        for (int mt = 0; mt < 4; ++mt)
#pragma unroll
            for (int nt = 0; nt < 4; ++nt)
                acc[mt][nt] = __builtin_amdgcn_mfma_f32_16x16x32_bf16(
                    af[mt], bfr[nt], acc[mt][nt], 0, 0, 0);
    }

#pragma unroll
    for (int nt = 0; nt < 4; ++nt) {
        int n = n0 + col_off + nt * 16 + n16;
        float bn = bias[n];
#pragma unroll
        for (int mt = 0; mt < 4; ++mt) {
            int mb = m0 + row_off + mt * 16 + g * 4;
#pragma unroll
            for (int r = 0; r < 4; ++r)
                out[(size_t)(mb + r) * N + n] = acc[mt][nt][r] + bn;
        }
    }
}

// ---------------------------------------------------------------------------
// RoPE in-place on q,k [B,H,T,D]; positions 1-indexed (t+1).
// ---------------------------------------------------------------------------
__global__ void rope_kernel(bf16_t* __restrict__ q, bf16_t* __restrict__ k) {
    int row = blockIdx.x * 4 + (threadIdx.x >> 6);  // (b*H+h)*T + t
    int d   = threadIdx.x & 63;
    int t   = row & (Tc - 1);
    float theta = powf(10000.0f, -(float)d * (1.0f / 64.0f));
    float ang   = (float)(t + 1) * theta;
    float sv, cv;
    sincosf(ang, &sv, &cv);
    size_t base = (size_t)row * Dc;
    float q1 = (float)q[base + d], q2 = (float)q[base + d + 64];
    q[base + d]      = (bf16_t)(q1 * cv - q2 * sv);
    q[base + d + 64] = (bf16_t)(q2 * cv + q1 * sv);
    float k1 = (float)k[base + d], k2 = (float)k[base + d + 64];
    k[base + d]      = (bf16_t)(k1 * cv - k2 * sv);
    k[base + d + 64] = (bf16_t)(k2 * cv + k1 * sv);
}

// ---------------------------------------------------------------------------
// Causal flash attention. q,k: [B,H,T,D] bf16; vt: [B,H,D,T] bf16;
// out att: [B,T,E] bf16. Block = 4 waves = 64 queries per q-tile.
// Block pi handles q-tiles {31-pi, pi}: uniform 33 K-tiles per block.
// 2 barriers/tile; next tile register-prefetched during compute; per-lane
// partial l with epilogue reduction; exp2-domain softmax.
// ---------------------------------------------------------------------------
constexpr int KP = 128 + 8;  // k_lds row pitch
constexpr int VP = 64 + 8;   // v_lds row pitch
constexpr int PP = 64 + 8;   // p_lds row pitch

__global__ __launch_bounds__(256) void attn_kernel(const bf16_t* __restrict__ q,
                                                   const bf16_t* __restrict__ kmat,
                                                   const bf16_t* __restrict__ vt,
                                                   bf16_t* __restrict__ out) {
    __shared__ __align__(16) bf16_t k_lds[64 * KP];
    __shared__ __align__(16) bf16_t v_lds[128 * VP];
    __shared__ __align__(16) bf16_t p_lds[4 * 16 * PP];

    const int tid  = threadIdx.x;
    const int wave = tid >> 6, lane = tid & 63;
    const int g = lane >> 4, n16 = lane & 15;
    const int pi = blockIdx.x;   // 0..15
    const int bh = blockIdx.y;
    const size_t base = (size_t)bh * Tc * Dc;
    const int b = bh >> 4, h = bh & 15;
    const float sc2 = 0.08838834764831845f * 1.4426950408889634f;  // /sqrt(D)*log2e
    bf16_t* pw = &p_lds[wave * 16 * PP];

    const int kr_key = tid >> 4, kr_c = tid & 15;   // K staging: per-i row i*16+kr_key
    const int vr_dd  = tid >> 3, vr_c = tid & 7;    // V staging: per-i row i*32+vr_dd

#pragma unroll 1
    for (int half = 0; half < 2; ++half) {
        const int qt = half ? pi : 31 - pi;
        const int q0 = qt * 64;

        bf16x8 qf[4];
        {
            const bf16_t* qp = q + base + (size_t)(q0 + wave * 16 + n16) * Dc + g * 8;
#pragma unroll
            for (int kk = 0; kk < 4; ++kk) qf[kk] = *(const bf16x8*)(qp + kk * 32);
        }

        float m_run[4], l_run[4];
#pragma unroll
        for (int r = 0; r < 4; ++r) { m_run[r] = -1e30f; l_run[r] = 0.0f; }
        f32x4 o_acc[8] = {};

        // preload tile 0 into registers
        bf16x8 rk[4], rv[4];
#pragma unroll
        for (int i = 0; i < 4; ++i)
            rk[i] = *(const bf16x8*)&kmat[base + (size_t)(i * 16 + kr_key) * Dc + kr_c * 8];
#pragma unroll
        for (int i = 0; i < 4; ++i)
            rv[i] = *(const bf16x8*)&vt[base + (size_t)(i * 32 + vr_dd) * Tc + vr_c * 8];

#pragma unroll 1
        for (int kt = 0; kt <= qt; ++kt) {
            const int k0 = kt * 64;
            __syncthreads();  // prior tile's LDS readers done
#pragma unroll
            for (int i = 0; i < 4; ++i)
                *(bf16x8*)&k_lds[(i * 16 + kr_key) * KP + kr_c * 8] = rk[i];
#pragma unroll
            for (int i = 0; i < 4; ++i)
                *(bf16x8*)&v_lds[(i * 32 + vr_dd) * VP + vr_c * 8] = rv[i];
            __syncthreads();  // staging visible

            if (kt < qt) {  // prefetch next tile (consumed at next ds_write)
                const int kn = k0 + 64;
#pragma unroll
                for (int i = 0; i < 4; ++i)
                    rk[i] = *(const bf16x8*)&kmat[base + (size_t)(kn + i * 16 + kr_key) * Dc + kr_c * 8];
#pragma unroll
                for (int i = 0; i < 4; ++i)
                    rv[i] = *(const bf16x8*)&vt[base + (size_t)(i * 32 + vr_dd) * Tc + kn + vr_c * 8];
            }

            // S = Q K^T (16 q x 64 keys per wave), pre-scaled to log2 domain
            f32x4 s_acc[4];
#pragma unroll
            for (int nt = 0; nt < 4; ++nt) {
                f32x4 a = {};
                int key = nt * 16 + n16;
#pragma unroll
                for (int kk = 0; kk < 4; ++kk) {
                    bf16x8 kf = *(const bf16x8*)&k_lds[key * KP + kk * 32 + g * 8];
                    a = __builtin_amdgcn_mfma_f32_16x16x32_bf16(qf[kk], kf, a, 0, 0, 0);
                }
                s_acc[nt] = a;
            }

            if (kt == qt) {  // diagonal: causal mask
#pragma unroll
                for (int nt = 0; nt < 4; ++nt) {
                    int key = k0 + nt * 16 + n16;
#pragma unroll
                    for (int r = 0; r < 4; ++r) {
                        int qq = q0 + wave * 16 + g * 4 + r;
                        float v = s_acc[nt][r] * sc2;
                        s_acc[nt][r] = (key <= qq) ? v : -1e30f;
                    }
                }
            } else {
#pragma unroll
                for (int nt = 0; nt < 4; ++nt)
#pragma unroll
                    for (int r = 0; r < 4; ++r) s_acc[nt][r] *= sc2;
            }

            // online softmax (exp2 domain); l kept as per-lane partial
            float alpha[4];
#pragma unroll
            for (int r = 0; r < 4; ++r) {
                float rm = fmaxf(fmaxf(s_acc[0][r], s_acc[1][r]),
                                 fmaxf(s_acc[2][r], s_acc[3][r]));
                rm = fmaxf(rm, __shfl_xor(rm, 1, 16));
                rm = fmaxf(rm, __shfl_xor(rm, 2, 16));
                rm = fmaxf(rm, __shfl_xor(rm, 4, 16));
                rm = fmaxf(rm, __shfl_xor(rm, 8, 16));
                float m_new = fmaxf(m_run[r], rm);
                alpha[r] = __builtin_amdgcn_exp2f(m_run[r] - m_new);
                m_run[r] = m_new;
                float sum = 0.0f;
#pragma unroll
                for (int nt = 0; nt < 4; ++nt) {
                    float p = __builtin_amdgcn_exp2f(s_acc[nt][r] - m_new);
                    s_acc[nt][r] = p;
                    sum += p;
                }
                l_run[r] = l_run[r] * alpha[r] + sum;  // per-lane partial
            }
#pragma unroll
            for (int dt = 0; dt < 8; ++dt)
#pragma unroll
                for (int r = 0; r < 4; ++r) o_acc[dt][r] *= alpha[r];

            // P (C/D) -> wave-private LDS [q][key]  (no barrier needed)
#pragma unroll
            for (int nt = 0; nt < 4; ++nt) {
                int key = nt * 16 + n16;
#pragma unroll
                for (int r = 0; r < 4; ++r)
                    pw[(g * 4 + r) * PP + key] = (bf16_t)s_acc[nt][r];
            }
            bf16x8 pf[2];
#pragma unroll
            for (int kk = 0; kk < 2; ++kk)
                pf[kk] = *(const bf16x8*)&pw[n16 * PP + kk * 32 + g * 8];

            // O += P V
#pragma unroll
            for (int dt = 0; dt < 8; ++dt) {
                int dd = dt * 16 + n16;
#pragma unroll
                for (int kk = 0; kk < 2; ++kk) {
                    bf16x8 vf = *(const bf16x8*)&v_lds[dd * VP + kk * 32 + g * 8];
                    o_acc[dt] = __builtin_amdgcn_mfma_f32_16x16x32_bf16(
                        pf[kk], vf, o_acc[dt], 0, 0, 0);
                }
            }
        }

        // epilogue: reduce per-lane l partials across the 16-lane row, write out
        float inv_l[4];
#pragma unroll
        for (int r = 0; r < 4; ++r) {
            float s = l_run[r];
            s += __shfl_xor(s, 1, 16);
            s += __shfl_xor(s, 2, 16);
            s += __shfl_xor(s, 4, 16);
            s += __shfl_xor(s, 8, 16);
            inv_l[r] = 1.0f / s;
        }
#pragma unroll
        for (int dt = 0; dt < 8; ++dt) {
            int d = dt * 16 + n16;
#pragma unroll
            for (int r = 0; r < 4; ++r) {
                int qq = q0 + wave * 16 + g * 4 + r;
                out[((size_t)(b * Tc + qq)) * Ec + h * Dc + d] =
                    (bf16_t)(o_acc[dt][r] * inv_l[r]);
            }
        }
    }
}

// ---------------------------------------------------------------------------
extern "C" void kernel_launch(void* const* d_in, const int* in_sizes, int n_in,
                              void* d_out, int out_size, void* d_ws, size_t ws_size,
                              hipStream_t stream) {
    const float* x  = (const float*)d_in[0];
    const float* Wq = (const float*)d_in[1];
    const float* bq = (const float*)d_in[2];
    const float* Wk = (const float*)d_in[3];
    const float* bk = (const float*)d_in[4];
    const float* Wv = (const float*)d_in[5];
    const float* bv = (const float*)d_in[6];
    const float* Wo = (const float*)d_in[7];
    const float* bo = (const float*)d_in[8];
    float* out = (float*)d_out;

    char* ws = (char*)d_ws;
    const size_t sz = (size_t)Bc * Hc * Tc * Dc * sizeof(bf16_t);  // 16.78 MB
    bf16_t* q   = (bf16_t*)(ws);            // R0
    bf16_t* k   = (bf16_t*)(ws + sz);       // R1
    bf16_t* vt  = (bf16_t*)(ws + 2 * sz);   // R2 (written transposed)
    bf16_t* xb  = (bf16_t*)(ws + 3 * sz);   // R3: xb, then att
    bf16_t* att = xb;

    convert_bf16<<<Mtok * Ec / (256 * 8), 256, 0, stream>>>(x, xb);
    gemm_qkv<<<dim3(Mtok / 128, 48), 256, 0, stream>>>(xb, Wq, Wk, Wv, bq, bk, bv,
                                                       q, k, vt);
    rope_kernel<<<Bc * Hc * Tc / 4, 256, 0, stream>>>(q, k);
    attn_kernel<<<dim3(16, Bc * Hc), 256, 0, stream>>>(q, k, vt, att);
    gemm_out<<<dim3(Mtok / 128, Ec / 128), 256, 0, stream>>>(att, Wo, bo, out,
                                                             Mtok, Ec, Ec);
}